// Round 5
// baseline (1180.266 us; speedup 1.0000x reference)
//
#include <hip/hip_runtime.h>
#include <hip/hip_bf16.h>

// Problem constants
#define S_LEN 2048
#define HID 4096
#define NH 32
#define NKV 8
#define HD 128
#define LDQKV 6144   // fused QKV output: cols [0,4096)=Q, [4096,5120)=K, [5120,6144)=V

typedef __bf16 bf16x8 __attribute__((ext_vector_type(8)));
typedef __bf16 bf16x4 __attribute__((ext_vector_type(4)));
typedef float f32x4 __attribute__((ext_vector_type(4)));

// async global->LDS, 16B per lane (HW: wave-uniform LDS base + lane*16)
#define GLD16(gp, lp)                                                                   \
    __builtin_amdgcn_global_load_lds((const __attribute__((address_space(1))) void*)(gp), \
                                     (__attribute__((address_space(3))) void*)(lp), 16, 0, 0)

// ---------------------------------------------------------------------------
// cast fp32 -> bf16 (vectorized 4/thread)
// ---------------------------------------------------------------------------
__global__ void cast_bf16_kernel(const float* __restrict__ x, __bf16* __restrict__ y, int n) {
    int i = (blockIdx.x * blockDim.x + threadIdx.x) * 4;
    if (i < n) {
        float4 v = *reinterpret_cast<const float4*>(x + i);
        bf16x4 o;
        o.x = (__bf16)v.x; o.y = (__bf16)v.y; o.z = (__bf16)v.z; o.w = (__bf16)v.w;
        *reinterpret_cast<bf16x4*>(y + i) = o;
    }
}

// ---------------------------------------------------------------------------
// transpose + cast: W [K][N] fp32 -> WT [N][K] bf16  (WT may be an offset view)
// ---------------------------------------------------------------------------
__global__ void transpose_cast_kernel(const float* __restrict__ W, __bf16* __restrict__ WT,
                                      int K, int N) {
    __shared__ float tile[32][33];
    int bx = blockIdx.x;  // over N/32
    int by = blockIdx.y;  // over K/32
    int tx = threadIdx.x; // 32
    int ty = threadIdx.y; // 8
    int n = bx * 32 + tx;
#pragma unroll
    for (int i = 0; i < 4; i++) {
        int k = by * 32 + ty + i * 8;
        tile[ty + i * 8][tx] = W[(size_t)k * N + n];
    }
    __syncthreads();
    int k2 = by * 32 + tx;
#pragma unroll
    for (int i = 0; i < 4; i++) {
        int n2 = bx * 32 + ty + i * 8;
        WT[(size_t)n2 * K + k2] = (__bf16)tile[tx][ty + i * 8];
    }
}

// ---------------------------------------------------------------------------
// strided bf16 transpose: V [R][C] (ld=ldin) -> VT [C][R] (ld=ldout)
// ---------------------------------------------------------------------------
__global__ void transpose_bf16_kernel(const __bf16* __restrict__ V, int ldin,
                                      __bf16* __restrict__ VT, int ldout) {
    __shared__ __bf16 tile[32][33];
    int bx = blockIdx.x;  // over C/32
    int by = blockIdx.y;  // over R/32
    int tx = threadIdx.x;
    int ty = threadIdx.y;
#pragma unroll
    for (int i = 0; i < 4; i++)
        tile[ty + i * 8][tx] = V[(size_t)(by * 32 + ty + i * 8) * ldin + bx * 32 + tx];
    __syncthreads();
#pragma unroll
    for (int i = 0; i < 4; i++)
        VT[(size_t)(bx * 32 + ty + i * 8) * ldout + by * 32 + tx] = tile[tx][ty + i * 8];
}

// ---------------------------------------------------------------------------
// NT GEMM (m97 structure): C[.,.] = A[M,K] * BT[N,K]^T, bf16 in, fp32 acc.
// 128x128 tile, BK=32, 4 waves, global_load_lds width-16 staging, unpadded LDS.
// ---------------------------------------------------------------------------
template <typename OUT_T>
__global__ __launch_bounds__(256) void gemm_bt_kernel(const __bf16* __restrict__ A, int lda,
                                                      const __bf16* __restrict__ BT, int ldb,
                                                      OUT_T* __restrict__ C, int ldc, int K) {
    __shared__ __bf16 As[128 * 32];
    __shared__ __bf16 Bs[128 * 32];
    int n0 = blockIdx.x * 128;
    int m0 = blockIdx.y * 128;
    int tid = threadIdx.x;
    int wave = tid >> 6, lane = tid & 63, quad = lane >> 4, l16 = lane & 15;
    int wm = (wave >> 1) * 64, wn = (wave & 1) * 64;
    int j0 = wave * 128 + lane;  // chunk ids handled by this lane: j0, j0+64

    f32x4 acc[4][4] = {};

    for (int kb = 0; kb < K; kb += 32) {
        __syncthreads();  // previous-iteration LDS reads done
#pragma unroll
        for (int q = 0; q < 2; q++) {
            int j = j0 + q * 64;
            int row = j >> 2, col8 = (j & 3) * 8;  // 512 chunks of 16B cover 128x32
            GLD16(&A[(size_t)(m0 + row) * lda + kb + col8], &As[j * 8]);
            GLD16(&BT[(size_t)(n0 + row) * ldb + kb + col8], &Bs[j * 8]);
        }
        __syncthreads();  // drains vmcnt (global_load_lds) + barrier
        bf16x8 af[4], bfr[4];
#pragma unroll
        for (int mt = 0; mt < 4; mt++)
            af[mt] = *reinterpret_cast<const bf16x8*>(&As[(wm + mt * 16 + l16) * 32 + quad * 8]);
#pragma unroll
        for (int nt = 0; nt < 4; nt++)
            bfr[nt] = *reinterpret_cast<const bf16x8*>(&Bs[(wn + nt * 16 + l16) * 32 + quad * 8]);
#pragma unroll
        for (int mt = 0; mt < 4; mt++)
#pragma unroll
            for (int nt = 0; nt < 4; nt++)
                acc[mt][nt] = __builtin_amdgcn_mfma_f32_16x16x32_bf16(af[mt], bfr[nt],
                                                                      acc[mt][nt], 0, 0, 0);
    }

#pragma unroll
    for (int mt = 0; mt < 4; mt++)
#pragma unroll
        for (int nt = 0; nt < 4; nt++)
#pragma unroll
            for (int r = 0; r < 4; r++) {
                int row = m0 + wm + mt * 16 + quad * 4 + r;
                int col = n0 + wn + nt * 16 + l16;
                C[(size_t)row * ldc + col] = (OUT_T)acc[mt][nt][r];
            }
}

// ---------------------------------------------------------------------------
// Flash attention v4 (causal, GQA) — BALANCED PAIRING.
// Block = (pair p, head h). It owns TWO 64-row Q tiles: low = tile p and
// high = tile 31-p. KV loop runs 32-p tiles of 64; low tile active for
// t <= p, high tile always => every block does exactly 33 m-tile
// activations (uniform makespan across all 512 blocks). K/V tiles staged
// into LDS once serve both Q tiles. O-rescale skipped when no new row max.
// ---------------------------------------------------------------------------
__global__ __launch_bounds__(256) void attn_kernel(const __bf16* __restrict__ QKV,
                                                   const __bf16* __restrict__ VT,
                                                   __bf16* __restrict__ Ao) {
    __shared__ __bf16 Ks[64 * 128];    // K tile [64 kv][128 d], chunk-swizzled
    __shared__ __bf16 Vs[128 * 64];    // V^T tile [128 d][64 kv], chunk-swizzled
    __shared__ __bf16 Pl[4][32 * 72];  // per-wave P buffer (+8 pad)
    int p = blockIdx.x;                // pair id 0..15 (p=0 stages most, first)
    int h = blockIdx.y;
    int kvh = h >> 2;                  // GQA
    int tid = threadIdx.x;
    int wave = tid >> 6, lane = tid & 63, quad = lane >> 4, l16 = lane & 15;
    int wqm[2];
    wqm[0] = 64 * p + wave * 16;        // low Q tile rows (active t <= p)
    wqm[1] = 64 * (31 - p) + wave * 16; // high Q tile rows (always active)
    const __bf16* Qb = QKV + (size_t)h * HD;
    const __bf16* Kb = QKV + HID + (size_t)kvh * HD;
    const __bf16* Vt = VT + (size_t)kvh * HD * S_LEN;
    __bf16* Pw = Pl[wave];

    // Q fragments, held for the whole KV loop (one-time scattered load)
    bf16x8 qf[2][4];
#pragma unroll
    for (int m = 0; m < 2; m++)
#pragma unroll
        for (int ks = 0; ks < 4; ks++)
            qf[m][ks] = *reinterpret_cast<const bf16x8*>(
                &Qb[(size_t)(wqm[m] + l16) * LDQKV + ks * 32 + quad * 8]);

    f32x4 acc_o[2][8] = {};
    float mst[2][4], lst[2][4];
#pragma unroll
    for (int m = 0; m < 2; m++)
#pragma unroll
        for (int r = 0; r < 4; r++) { mst[m][r] = -1e30f; lst[m][r] = 0.f; }

    const float scale2 = 0.12751743f;  // (1/sqrt(128)) * log2(e)
    int ntiles = 32 - p;               // high tile's causal trip count

    for (int t = 0; t < ntiles; t++) {
        int kv0 = t << 6;
        int mlo = (t <= p) ? 0 : 1;    // low tile participates while t <= p
        __syncthreads();  // previous tile's LDS reads done
        // ---- stage K tile: 64 rows x 16 chunks of 16B (1024 chunks)
#pragma unroll
        for (int i = 0; i < 4; i++) {
            int c = i * 256 + tid;
            int row = c >> 4, sub = c & 15;
            int col8 = sub ^ (row & 15);  // source-side XOR swizzle
            GLD16(&Kb[(size_t)(kv0 + row) * LDQKV + col8 * 8], &Ks[c * 8]);
        }
        // ---- stage V^T tile: 128 rows x 8 chunks of 16B (1024 chunks)
#pragma unroll
        for (int i = 0; i < 4; i++) {
            int c = i * 256 + tid;
            int row = c >> 3, sub = c & 7;
            int col8 = sub ^ (row & 7);
            GLD16(&Vt[(size_t)row * S_LEN + kv0 + col8 * 8], &Vs[c * 8]);
        }
        __syncthreads();  // drains vmcnt + barrier

        // ---- S = Q K^T for active m-tiles
        f32x4 sacc[2][4] = {};
#pragma unroll
        for (int ks = 0; ks < 4; ks++) {
            bf16x8 kf[4];
#pragma unroll
            for (int n = 0; n < 4; n++) {
                int row = n * 16 + l16;
                int sub = (ks * 4 + quad) ^ l16;  // row&15 == l16
                kf[n] = *reinterpret_cast<const bf16x8*>(&Ks[row * 128 + sub * 8]);
            }
            for (int m = mlo; m < 2; m++)
#pragma unroll
                for (int n = 0; n < 4; n++)
                    sacc[m][n] = __builtin_amdgcn_mfma_f32_16x16x32_bf16(
                        qf[m][ks], kf[n], sacc[m][n], 0, 0, 0);
        }
        // ---- online softmax (base-2); rows on (quad,r), cols on (n,l16)
        for (int m = mlo; m < 2; m++) {
#pragma unroll
            for (int r = 0; r < 4; r++) {
                int row = wqm[m] + quad * 4 + r;
                float vals[4], rowmax = -1e30f;
#pragma unroll
                for (int n = 0; n < 4; n++) {
                    int col = kv0 + n * 16 + l16;
                    float v = sacc[m][n][r] * scale2;
                    if (col > row) v = -1e30f;  // causal
                    vals[n] = v;
                    rowmax = fmaxf(rowmax, v);
                }
                rowmax = fmaxf(rowmax, __shfl_xor(rowmax, 8, 16));
                rowmax = fmaxf(rowmax, __shfl_xor(rowmax, 4, 16));
                rowmax = fmaxf(rowmax, __shfl_xor(rowmax, 2, 16));
                rowmax = fmaxf(rowmax, __shfl_xor(rowmax, 1, 16));
                float mold = mst[m][r];
                float mnew = fmaxf(mold, rowmax);
                float rsum = 0.f;
#pragma unroll
                for (int n = 0; n < 4; n++) {
                    float pp = __builtin_amdgcn_exp2f(vals[n] - mnew);
                    rsum += pp;
                    Pw[(m * 16 + quad * 4 + r) * 72 + n * 16 + l16] = (__bf16)pp;
                }
                rsum += __shfl_xor(rsum, 8, 16);
                rsum += __shfl_xor(rsum, 4, 16);
                rsum += __shfl_xor(rsum, 2, 16);
                rsum += __shfl_xor(rsum, 1, 16);
                if (rowmax > mold) {  // new max: rescale path (alpha < 1)
                    float alpha = __builtin_amdgcn_exp2f(mold - mnew);
                    mst[m][r] = mnew;
                    lst[m][r] = lst[m][r] * alpha + rsum;
#pragma unroll
                    for (int dn = 0; dn < 8; dn++)
                        acc_o[m][dn][r] *= alpha;
                } else {              // alpha == 1 exactly: skip 32 mults
                    lst[m][r] += rsum;
                }
            }
        }
        // ---- O += P V (P: same-wave LDS, no barrier; V from swizzled LDS)
#pragma unroll
        for (int ks = 0; ks < 2; ks++) {
            bf16x8 pf[2];
            for (int m = mlo; m < 2; m++)
                pf[m] = *reinterpret_cast<const bf16x8*>(
                    &Pw[(m * 16 + l16) * 72 + ks * 32 + quad * 8]);
#pragma unroll
            for (int dn = 0; dn < 8; dn++) {
                int row = dn * 16 + l16;
                int sub = (ks * 4 + quad) ^ (row & 7);
                bf16x8 vf = *reinterpret_cast<const bf16x8*>(&Vs[row * 64 + sub * 8]);
                for (int m = mlo; m < 2; m++)
                    acc_o[m][dn] = __builtin_amdgcn_mfma_f32_16x16x32_bf16(
                        pf[m], vf, acc_o[m][dn], 0, 0, 0);
            }
        }
    }

    // ---- epilogue: normalize and store both Q tiles
#pragma unroll
    for (int m = 0; m < 2; m++) {
        float rl[4];
#pragma unroll
        for (int r = 0; r < 4; r++) rl[r] = 1.0f / lst[m][r];
#pragma unroll
        for (int dn = 0; dn < 8; dn++)
#pragma unroll
            for (int r = 0; r < 4; r++) {
                int row = wqm[m] + quad * 4 + r;
                int col = h * HD + dn * 16 + l16;
                Ao[(size_t)row * HID + col] = (__bf16)(acc_o[m][dn][r] * rl[r]);
            }
    }
}

// ---------------------------------------------------------------------------
extern "C" void kernel_launch(void* const* d_in, const int* in_sizes, int n_in,
                              void* d_out, int out_size, void* d_ws, size_t ws_size,
                              hipStream_t stream) {
    const float* hs = (const float*)d_in[0];
    // d_in[1] = attention_mask (pure causal; applied analytically)
    const float* wq = (const float*)d_in[2];
    const float* wk = (const float*)d_in[3];
    const float* wv = (const float*)d_in[4];
    const float* wo = (const float*)d_in[5];
    float* out = (float*)d_out;

    char* ws = (char*)d_ws;
    // workspace (92 MB with reuse)
    __bf16* WqkvT = (__bf16*)(ws + (size_t)0);          // 48 MB [6144][4096]; reused for WoT
    __bf16* Xb    = (__bf16*)(ws + ((size_t)48 << 20)); // 16 MB [2048][4096]; reused for attn out
    __bf16* QKV   = (__bf16*)(ws + ((size_t)64 << 20)); // 24 MB [2048][6144]
    __bf16* VTg   = (__bf16*)(ws + ((size_t)88 << 20)); //  4 MB [1024][2048]
    __bf16* Ab    = Xb;

    const int nX = S_LEN * HID;  // 8M

    // 1) cast hidden to bf16
    cast_bf16_kernel<<<nX / 4 / 256, 256, 0, stream>>>(hs, Xb, nX);
    // 2) fused W_{q,k,v}^T into one [6144][4096] bf16 buffer
    transpose_cast_kernel<<<dim3(128, 128), dim3(32, 8), 0, stream>>>(wq, WqkvT, HID, HID);
    transpose_cast_kernel<<<dim3(32, 128), dim3(32, 8), 0, stream>>>(
        wk, WqkvT + (size_t)4096 * HID, HID, NKV * HD);
    transpose_cast_kernel<<<dim3(32, 128), dim3(32, 8), 0, stream>>>(
        wv, WqkvT + (size_t)5120 * HID, HID, NKV * HD);
    // 3) one fused QKV GEMM: [2048][6144]
    gemm_bt_kernel<__bf16><<<dim3(LDQKV / 128, S_LEN / 128), 256, 0, stream>>>(
        Xb, HID, WqkvT, HID, QKV, LDQKV, HID);
    // 4) V^T for PV B-operand (V = QKV cols 5120..6143)
    transpose_bf16_kernel<<<dim3(32, 64), dim3(32, 8), 0, stream>>>(
        QKV + 5120, LDQKV, VTg, S_LEN);
    // 5) flash attention (balanced pairing) -> Ab (overwrites Xb)
    attn_kernel<<<dim3(16, 32), 256, 0, stream>>>(QKV, VTg, Ab);
    // 6) out = Ab @ WoT^T (fp32). WoT reuses WqkvT space.
    transpose_cast_kernel<<<dim3(128, 128), dim3(32, 8), 0, stream>>>(wo, WqkvT, HID, HID);
    gemm_bt_kernel<float><<<dim3(HID / 128, S_LEN / 128), 256, 0, stream>>>(
        Ab, HID, WqkvT, HID, out, HID, HID);
}

// Round 6
// 619.964 us; speedup vs baseline: 1.9038x; 1.9038x over previous
//
#include <hip/hip_runtime.h>
#include <hip/hip_bf16.h>

// Problem constants
#define S_LEN 2048
#define HID 4096
#define NH 32
#define NKV 8
#define HD 128
#define LDQKV 6144   // fused QKV output: cols [0,4096)=Q, [4096,5120)=K, [5120,6144)=V

typedef __bf16 bf16x8 __attribute__((ext_vector_type(8)));
typedef __bf16 bf16x4 __attribute__((ext_vector_type(4)));
typedef float f32x4 __attribute__((ext_vector_type(4)));

// async global->LDS, 16B per lane (HW: wave-uniform LDS base + lane*16)
#define GLD16(gp, lp)                                                                   \
    __builtin_amdgcn_global_load_lds((const __attribute__((address_space(1))) void*)(gp), \
                                     (__attribute__((address_space(3))) void*)(lp), 16, 0, 0)

// ---------------------------------------------------------------------------
// cast fp32 -> bf16 (vectorized 4/thread)
// ---------------------------------------------------------------------------
__global__ void cast_bf16_kernel(const float* __restrict__ x, __bf16* __restrict__ y, int n) {
    int i = (blockIdx.x * blockDim.x + threadIdx.x) * 4;
    if (i < n) {
        float4 v = *reinterpret_cast<const float4*>(x + i);
        bf16x4 o;
        o.x = (__bf16)v.x; o.y = (__bf16)v.y; o.z = (__bf16)v.z; o.w = (__bf16)v.w;
        *reinterpret_cast<bf16x4*>(y + i) = o;
    }
}

// ---------------------------------------------------------------------------
// transpose + cast: W [K][N] fp32 -> WT [N][K] bf16  (WT may be an offset view)
// ---------------------------------------------------------------------------
__global__ void transpose_cast_kernel(const float* __restrict__ W, __bf16* __restrict__ WT,
                                      int K, int N) {
    __shared__ float tile[32][33];
    int bx = blockIdx.x;  // over N/32
    int by = blockIdx.y;  // over K/32
    int tx = threadIdx.x; // 32
    int ty = threadIdx.y; // 8
    int n = bx * 32 + tx;
#pragma unroll
    for (int i = 0; i < 4; i++) {
        int k = by * 32 + ty + i * 8;
        tile[ty + i * 8][tx] = W[(size_t)k * N + n];
    }
    __syncthreads();
    int k2 = by * 32 + tx;
#pragma unroll
    for (int i = 0; i < 4; i++) {
        int n2 = bx * 32 + ty + i * 8;
        WT[(size_t)n2 * K + k2] = (__bf16)tile[tx][ty + i * 8];
    }
}

// ---------------------------------------------------------------------------
// strided bf16 transpose: V [R][C] (ld=ldin) -> VT [C][R] (ld=ldout)
// ---------------------------------------------------------------------------
__global__ void transpose_bf16_kernel(const __bf16* __restrict__ V, int ldin,
                                      __bf16* __restrict__ VT, int ldout) {
    __shared__ __bf16 tile[32][33];
    int bx = blockIdx.x;  // over C/32
    int by = blockIdx.y;  // over R/32
    int tx = threadIdx.x;
    int ty = threadIdx.y;
#pragma unroll
    for (int i = 0; i < 4; i++)
        tile[ty + i * 8][tx] = V[(size_t)(by * 32 + ty + i * 8) * ldin + bx * 32 + tx];
    __syncthreads();
#pragma unroll
    for (int i = 0; i < 4; i++)
        VT[(size_t)(bx * 32 + ty + i * 8) * ldout + by * 32 + tx] = tile[tx][ty + i * 8];
}

// ---------------------------------------------------------------------------
// NT GEMM (m97 structure): C[.,.] = A[M,K] * BT[N,K]^T, bf16 in, fp32 acc.
// 128x128 tile, BK=32, 4 waves, global_load_lds width-16 staging, unpadded LDS.
// ---------------------------------------------------------------------------
template <typename OUT_T>
__global__ __launch_bounds__(256) void gemm_bt_kernel(const __bf16* __restrict__ A, int lda,
                                                      const __bf16* __restrict__ BT, int ldb,
                                                      OUT_T* __restrict__ C, int ldc, int K) {
    __shared__ __bf16 As[128 * 32];
    __shared__ __bf16 Bs[128 * 32];
    int n0 = blockIdx.x * 128;
    int m0 = blockIdx.y * 128;
    int tid = threadIdx.x;
    int wave = tid >> 6, lane = tid & 63, quad = lane >> 4, l16 = lane & 15;
    int wm = (wave >> 1) * 64, wn = (wave & 1) * 64;
    int j0 = wave * 128 + lane;  // chunk ids handled by this lane: j0, j0+64

    f32x4 acc[4][4] = {};

    for (int kb = 0; kb < K; kb += 32) {
        __syncthreads();  // previous-iteration LDS reads done
#pragma unroll
        for (int q = 0; q < 2; q++) {
            int j = j0 + q * 64;
            int row = j >> 2, col8 = (j & 3) * 8;  // 512 chunks of 16B cover 128x32
            GLD16(&A[(size_t)(m0 + row) * lda + kb + col8], &As[j * 8]);
            GLD16(&BT[(size_t)(n0 + row) * ldb + kb + col8], &Bs[j * 8]);
        }
        __syncthreads();  // drains vmcnt (global_load_lds) + barrier
        bf16x8 af[4], bfr[4];
#pragma unroll
        for (int mt = 0; mt < 4; mt++)
            af[mt] = *reinterpret_cast<const bf16x8*>(&As[(wm + mt * 16 + l16) * 32 + quad * 8]);
#pragma unroll
        for (int nt = 0; nt < 4; nt++)
            bfr[nt] = *reinterpret_cast<const bf16x8*>(&Bs[(wn + nt * 16 + l16) * 32 + quad * 8]);
#pragma unroll
        for (int mt = 0; mt < 4; mt++)
#pragma unroll
            for (int nt = 0; nt < 4; nt++)
                acc[mt][nt] = __builtin_amdgcn_mfma_f32_16x16x32_bf16(af[mt], bfr[nt],
                                                                      acc[mt][nt], 0, 0, 0);
    }

#pragma unroll
    for (int mt = 0; mt < 4; mt++)
#pragma unroll
        for (int nt = 0; nt < 4; nt++)
#pragma unroll
            for (int r = 0; r < 4; r++) {
                int row = m0 + wm + mt * 16 + quad * 4 + r;
                int col = n0 + wn + nt * 16 + l16;
                C[(size_t)row * ldc + col] = (OUT_T)acc[mt][nt][r];
            }
}

// ---------------------------------------------------------------------------
// Flash attention v5 (causal, GQA) — balanced pairing, UNROLLED m-loops.
// Block = (pair p, head h): low Q tile p (active t <= p) + high Q tile 31-p
// (always active); KV loop 32-p tiles => every block 33 m-tile activations.
// All m-loops compile-time unrolled with a uniform `continue` guard so the
// accumulators stay in registers (round-5's runtime bound spilled to scratch).
// ---------------------------------------------------------------------------
__global__ __launch_bounds__(256) void attn_kernel(const __bf16* __restrict__ QKV,
                                                   const __bf16* __restrict__ VT,
                                                   __bf16* __restrict__ Ao) {
    __shared__ __bf16 Ks[64 * 128];    // K tile [64 kv][128 d], chunk-swizzled
    __shared__ __bf16 Vs[128 * 64];    // V^T tile [128 d][64 kv], chunk-swizzled
    __shared__ __bf16 Pl[4][32 * 72];  // per-wave P buffer (+8 pad)
    int p = blockIdx.x;                // pair id 0..15
    int h = blockIdx.y;
    int kvh = h >> 2;                  // GQA
    int tid = threadIdx.x;
    int wave = tid >> 6, lane = tid & 63, quad = lane >> 4, l16 = lane & 15;
    int wq0 = 64 * p + wave * 16;        // low Q tile rows (active t <= p)
    int wq1 = 64 * (31 - p) + wave * 16; // high Q tile rows (always active)
    const __bf16* Qb = QKV + (size_t)h * HD;
    const __bf16* Kb = QKV + HID + (size_t)kvh * HD;
    const __bf16* Vt = VT + (size_t)kvh * HD * S_LEN;
    __bf16* Pw = Pl[wave];

    // Q fragments, held for the whole KV loop (one-time scattered load)
    bf16x8 qf[2][4];
#pragma unroll
    for (int m = 0; m < 2; m++)
#pragma unroll
        for (int ks = 0; ks < 4; ks++)
            qf[m][ks] = *reinterpret_cast<const bf16x8*>(
                &Qb[(size_t)((m ? wq1 : wq0) + l16) * LDQKV + ks * 32 + quad * 8]);

    f32x4 acc_o[2][8] = {};
    float mst[2][4], lst[2][4];
#pragma unroll
    for (int m = 0; m < 2; m++)
#pragma unroll
        for (int r = 0; r < 4; r++) { mst[m][r] = -1e30f; lst[m][r] = 0.f; }

    const float scale2 = 0.12751743f;  // (1/sqrt(128)) * log2(e)
    int ntiles = 32 - p;               // high tile's causal trip count

    for (int t = 0; t < ntiles; t++) {
        int kv0 = t << 6;
        bool lo_act = (t <= p);        // low tile participates while t <= p
        __syncthreads();  // previous tile's LDS reads done
        // ---- stage K tile: 64 rows x 16 chunks of 16B (1024 chunks)
#pragma unroll
        for (int i = 0; i < 4; i++) {
            int c = i * 256 + tid;
            int row = c >> 4, sub = c & 15;
            int col8 = sub ^ (row & 15);  // source-side XOR swizzle
            GLD16(&Kb[(size_t)(kv0 + row) * LDQKV + col8 * 8], &Ks[c * 8]);
        }
        // ---- stage V^T tile: 128 rows x 8 chunks of 16B (1024 chunks)
#pragma unroll
        for (int i = 0; i < 4; i++) {
            int c = i * 256 + tid;
            int row = c >> 3, sub = c & 7;
            int col8 = sub ^ (row & 7);
            GLD16(&Vt[(size_t)row * S_LEN + kv0 + col8 * 8], &Vs[c * 8]);
        }
        __syncthreads();  // drains vmcnt + barrier

        // ---- S = Q K^T (m unrolled; uniform skip for inactive low tile)
        f32x4 sacc[2][4] = {};
#pragma unroll
        for (int ks = 0; ks < 4; ks++) {
            bf16x8 kf[4];
#pragma unroll
            for (int n = 0; n < 4; n++) {
                int row = n * 16 + l16;
                int sub = (ks * 4 + quad) ^ l16;  // row&15 == l16
                kf[n] = *reinterpret_cast<const bf16x8*>(&Ks[row * 128 + sub * 8]);
            }
#pragma unroll
            for (int m = 0; m < 2; m++) {
                if (m == 0 && !lo_act) continue;
#pragma unroll
                for (int n = 0; n < 4; n++)
                    sacc[m][n] = __builtin_amdgcn_mfma_f32_16x16x32_bf16(
                        qf[m][ks], kf[n], sacc[m][n], 0, 0, 0);
            }
        }
        // ---- online softmax (base-2); rows on (quad,r), cols on (n,l16)
#pragma unroll
        for (int m = 0; m < 2; m++) {
            if (m == 0 && !lo_act) continue;
            int wq = m ? wq1 : wq0;
#pragma unroll
            for (int r = 0; r < 4; r++) {
                int row = wq + quad * 4 + r;
                float vals[4], rowmax = -1e30f;
#pragma unroll
                for (int n = 0; n < 4; n++) {
                    int col = kv0 + n * 16 + l16;
                    float v = sacc[m][n][r] * scale2;
                    if (col > row) v = -1e30f;  // causal
                    vals[n] = v;
                    rowmax = fmaxf(rowmax, v);
                }
                rowmax = fmaxf(rowmax, __shfl_xor(rowmax, 8, 16));
                rowmax = fmaxf(rowmax, __shfl_xor(rowmax, 4, 16));
                rowmax = fmaxf(rowmax, __shfl_xor(rowmax, 2, 16));
                rowmax = fmaxf(rowmax, __shfl_xor(rowmax, 1, 16));
                float mold = mst[m][r];
                float mnew = fmaxf(mold, rowmax);
                float alpha = __builtin_amdgcn_exp2f(mold - mnew);
                mst[m][r] = mnew;
                float rsum = 0.f;
#pragma unroll
                for (int n = 0; n < 4; n++) {
                    float pp = __builtin_amdgcn_exp2f(vals[n] - mnew);
                    rsum += pp;
                    Pw[(m * 16 + quad * 4 + r) * 72 + n * 16 + l16] = (__bf16)pp;
                }
                rsum += __shfl_xor(rsum, 8, 16);
                rsum += __shfl_xor(rsum, 4, 16);
                rsum += __shfl_xor(rsum, 2, 16);
                rsum += __shfl_xor(rsum, 1, 16);
                lst[m][r] = lst[m][r] * alpha + rsum;
#pragma unroll
                for (int dn = 0; dn < 8; dn++)
                    acc_o[m][dn][r] *= alpha;
            }
        }
        // ---- O += P V (P: same-wave LDS, no barrier; V from swizzled LDS)
#pragma unroll
        for (int ks = 0; ks < 2; ks++) {
            bf16x8 pf[2];
#pragma unroll
            for (int m = 0; m < 2; m++) {
                if (m == 0 && !lo_act) continue;
                pf[m] = *reinterpret_cast<const bf16x8*>(
                    &Pw[(m * 16 + l16) * 72 + ks * 32 + quad * 8]);
            }
#pragma unroll
            for (int dn = 0; dn < 8; dn++) {
                int row = dn * 16 + l16;
                int sub = (ks * 4 + quad) ^ (row & 7);
                bf16x8 vf = *reinterpret_cast<const bf16x8*>(&Vs[row * 64 + sub * 8]);
#pragma unroll
                for (int m = 0; m < 2; m++) {
                    if (m == 0 && !lo_act) continue;
                    acc_o[m][dn] = __builtin_amdgcn_mfma_f32_16x16x32_bf16(
                        pf[m], vf, acc_o[m][dn], 0, 0, 0);
                }
            }
        }
    }

    // ---- epilogue: normalize and store both Q tiles
#pragma unroll
    for (int m = 0; m < 2; m++) {
        int wq = m ? wq1 : wq0;
        float rl[4];
#pragma unroll
        for (int r = 0; r < 4; r++) rl[r] = 1.0f / lst[m][r];
#pragma unroll
        for (int dn = 0; dn < 8; dn++)
#pragma unroll
            for (int r = 0; r < 4; r++) {
                int row = wq + quad * 4 + r;
                int col = h * HD + dn * 16 + l16;
                Ao[(size_t)row * HID + col] = (__bf16)(acc_o[m][dn][r] * rl[r]);
            }
    }
}

// ---------------------------------------------------------------------------
extern "C" void kernel_launch(void* const* d_in, const int* in_sizes, int n_in,
                              void* d_out, int out_size, void* d_ws, size_t ws_size,
                              hipStream_t stream) {
    const float* hs = (const float*)d_in[0];
    // d_in[1] = attention_mask (pure causal; applied analytically)
    const float* wq = (const float*)d_in[2];
    const float* wk = (const float*)d_in[3];
    const float* wv = (const float*)d_in[4];
    const float* wo = (const float*)d_in[5];
    float* out = (float*)d_out;

    char* ws = (char*)d_ws;
    // workspace (92 MB with reuse)
    __bf16* WqkvT = (__bf16*)(ws + (size_t)0);          // 48 MB [6144][4096]; reused for WoT
    __bf16* Xb    = (__bf16*)(ws + ((size_t)48 << 20)); // 16 MB [2048][4096]; reused for attn out
    __bf16* QKV   = (__bf16*)(ws + ((size_t)64 << 20)); // 24 MB [2048][6144]
    __bf16* VTg   = (__bf16*)(ws + ((size_t)88 << 20)); //  4 MB [1024][2048]
    __bf16* Ab    = Xb;

    const int nX = S_LEN * HID;  // 8M

    // 1) cast hidden to bf16
    cast_bf16_kernel<<<nX / 4 / 256, 256, 0, stream>>>(hs, Xb, nX);
    // 2) fused W_{q,k,v}^T into one [6144][4096] bf16 buffer
    transpose_cast_kernel<<<dim3(128, 128), dim3(32, 8), 0, stream>>>(wq, WqkvT, HID, HID);
    transpose_cast_kernel<<<dim3(32, 128), dim3(32, 8), 0, stream>>>(
        wk, WqkvT + (size_t)4096 * HID, HID, NKV * HD);
    transpose_cast_kernel<<<dim3(32, 128), dim3(32, 8), 0, stream>>>(
        wv, WqkvT + (size_t)5120 * HID, HID, NKV * HD);
    // 3) one fused QKV GEMM: [2048][6144]
    gemm_bt_kernel<__bf16><<<dim3(LDQKV / 128, S_LEN / 128), 256, 0, stream>>>(
        Xb, HID, WqkvT, HID, QKV, LDQKV, HID);
    // 4) V^T for PV B-operand (V = QKV cols 5120..6143)
    transpose_bf16_kernel<<<dim3(32, 64), dim3(32, 8), 0, stream>>>(
        QKV + 5120, LDQKV, VTg, S_LEN);
    // 5) flash attention (balanced pairing) -> Ab (overwrites Xb)
    attn_kernel<<<dim3(16, 32), 256, 0, stream>>>(QKV, VTg, Ab);
    // 6) out = Ab @ WoT^T (fp32). WoT reuses WqkvT space.
    transpose_cast_kernel<<<dim3(128, 128), dim3(32, 8), 0, stream>>>(wo, WqkvT, HID, HID);
    gemm_bt_kernel<float><<<dim3(HID / 128, S_LEN / 128), 256, 0, stream>>>(
        Ab, HID, WqkvT, HID, out, HID, HID);
}